// Round 14
// baseline (124.412 us; speedup 1.0000x reference)
//
#include <hip/hip_runtime.h>

// Bilinear backward warp: img [B,C,H,W] f32, flo [B,2,H,W] f32 -> out [B,C,H,W] f32
// B=8, C=64, H=256, W=448
//
// R14: halo-restage reduction. R7 staged 10 rows per 4 output rows (2.5x
// L2->LDS overfetch). Now 8 output rows per block (448 threads, 8 px each,
// column-owner), BAND=14 (1.75x), ONE channel per round with the proven
// 2-buffer __syncthreads skeleton. LDS 50.2KB -> 3 blocks/CU resident.
// Per block-round: 25KB staged (was 36), 14KB output (same), same DS taps.

#define BN 8
#define CN 64
#define HN 256
#define WN 448
#define HW (HN * WN)
#define R 8              // output rows per block
#define BAND 14          // staged rows: lo = h0-3 .. h0+10
#define BWORDS (BAND * WN)    // 6272 words
#define TPB WN           // 448 threads = 7 waves
#define NXCD 8
#define CSPLIT 4
#define CLOOP (CN / CSPLIT)   // 16 channels per block == rounds

typedef __attribute__((address_space(1))) const void glb_v;
typedef __attribute__((address_space(3))) void lds_v;

__global__ __launch_bounds__(TPB) void warp_kernel(const float* __restrict__ img,
                                                   const float* __restrict__ flo,
                                                   float* __restrict__ out) {
    // 2 buffers x (6272+4) floats = 50208 B -> 3 blocks/CU
    __shared__ float lds[2][BWORDS + 4];

    // XCD swizzle: 1024 blocks = 128/XCD = one batch per XCD; the 4
    // channel-quarters of a row-tile are adjacent wgids -> share L2 bands.
    const int nwg = gridDim.x;            // 1024
    const int cpx = nwg / NXCD;           // 128
    const int bid = blockIdx.x;
    const int wgid = (bid % NXCD) * cpx + (bid / NXCD);

    const int b    = wgid / cpx;          // 0..7
    const int rem  = wgid % cpx;          // 0..127
    const int tile = rem >> 2;            // 0..31 (row tile)
    const int ch0  = (rem & 3) * CLOOP;   // 0,16,32,48
    const int h0   = tile * R;
    const int w    = threadIdx.x;         // 0..447 (column owner)

    int lo = h0 - 3;
    lo = lo < 0 ? 0 : (lo > HN - BAND ? HN - BAND : lo);

    const float* imgb = img + (size_t)b * CN * HW;
    const float* flob = flo + (size_t)b * 2 * HW;

    // ---- per-pixel setup: 8 rows of this column, channel-invariant ----
    float wa[R], wb[R], wc[R], wd[R];
    int sA[R], sB[R];       // band-relative LDS word offsets (row-clamped)
    int gA[R], gB[R];       // plane-relative global word offsets (fallback)
    int dx_[R];
    bool fb[R];
    bool anyfb = false;
#pragma unroll
    for (int r = 0; r < R; ++r) {
        const int h = h0 + r;
        const int hw = h * WN + w;
        const float fx = flob[hw];
        const float fy = flob[HW + hw];
        const float x = (float)w + fx;
        const float y = (float)h + fy;
        int x0 = (int)x;                 // trunc toward zero (matches ref)
        int x1 = x0 + 1;
        int y0 = (int)y;
        int y1 = y0 + 1;
        x0 = min(max(x0, 0), WN - 1);
        x1 = min(max(x1, 0), WN - 1);
        y0 = min(max(y0, 0), HN - 1);
        y1 = min(max(y1, 0), HN - 1);
        const float x0f = (float)x0, x1f = (float)x1;
        const float y0f = (float)y0, y1f = (float)y1;
        wa[r] = (x1f - x) * (y1f - y);
        wb[r] = (x1f - x) * (y - y0f);
        wc[r] = (x - x0f) * (y1f - y);
        wd[r] = (x - x0f) * (y - y0f);
        dx_[r] = x1 - x0;                // 0 only at l/r edge clip
        const bool inband = (y0 >= lo) && (y1 <= lo + BAND - 1);
        fb[r] = !inband;
        anyfb |= fb[r];
        const int rA = min(max(y0 - lo, 0), BAND - 1);
        const int rB = min(max(y1 - lo, 0), BAND - 1);
        sA[r] = rA * WN + x0;
        sB[r] = rB * WN + x0;
        gA[r] = y0 * WN + x0;
        gB[r] = y1 * WN + x0;
    }
    const bool dirty = __any(anyfb);    // wave-uniform, rare

    const int wave = threadIdx.x >> 6;   // 0..6
    const int lane = threadIdx.x & 63;

    // ---- staging: 14 rows x 448 = 6272 words = 24 x 1KB chunks + 128-word tail
    //      waves 0-2: chunks {w, w+7, w+14, 21+w}; waves 3-6: {w, w+7, w+14};
    //      tail: waves 3,4 do one width-4 load (64 words each). Max 4 instr/wave.
    auto stage = [&](int bufi, int c) {          // c = global channel
        const float* src = imgb + (size_t)c * HW + (size_t)lo * WN;
        float* dst = &lds[bufi][0];
#pragma unroll
        for (int s = wave; s < 21; s += 7) {
            __builtin_amdgcn_global_load_lds(
                (glb_v*)(src + s * 256 + lane * 4),
                (lds_v*)(dst + s * 256), 16, 0, 0);
        }
        if (wave < 3) {
            const int s = 21 + wave;
            __builtin_amdgcn_global_load_lds(
                (glb_v*)(src + s * 256 + lane * 4),
                (lds_v*)(dst + s * 256), 16, 0, 0);
        } else if (wave < 5) {
            const int base = 24 * 256 + (wave - 3) * 64;
            __builtin_amdgcn_global_load_lds(
                (glb_v*)(src + base + lane),
                (lds_v*)(dst + base), 4, 0, 0);
        }
    };

    stage(0, ch0);
    __syncthreads();

    float* outp = out + (size_t)b * CN * HW + (size_t)ch0 * HW + (size_t)h0 * WN + w;

    for (int cl = 0; cl < CLOOP; ++cl) {
        if (cl + 1 < CLOOP) stage((cl + 1) & 1, ch0 + cl + 1);

        const float* buf = &lds[cl & 1][0];
        float o[R];
        if (!dirty) {
#pragma unroll
            for (int r = 0; r < R; ++r) {
                const float a0 = buf[sA[r]];
                const float a1 = buf[sA[r] + 1];   // ds_read2_b32 pair
                const float b0 = buf[sB[r]];
                const float b1 = buf[sB[r] + 1];
                const float Ic = dx_[r] ? a1 : a0;
                const float Id = dx_[r] ? b1 : b0;
                o[r] = wa[r] * a0 + wb[r] * b0 + wc[r] * Ic + wd[r] * Id;
            }
        } else {
            const float* pg = imgb + (size_t)(ch0 + cl) * HW;
#pragma unroll
            for (int r = 0; r < R; ++r) {
                float a0 = buf[sA[r]];
                float a1 = buf[sA[r] + 1];
                float b0 = buf[sB[r]];
                float b1 = buf[sB[r] + 1];
                if (fb[r]) {
                    a0 = pg[gA[r]];
                    a1 = pg[gA[r] + dx_[r]];
                    b0 = pg[gB[r]];
                    b1 = pg[gB[r] + dx_[r]];
                }
                const float Ic = dx_[r] ? a1 : a0;
                const float Id = dx_[r] ? b1 : b0;
                o[r] = wa[r] * a0 + wb[r] * b0 + wc[r] * Ic + wd[r] * Id;
            }
        }
#pragma unroll
        for (int r = 0; r < R; ++r) {
            outp[(size_t)cl * HW + r * WN] = o[r];
        }
        __syncthreads();   // drain (stage cl+1 landed) + barrier, once per channel
    }
}

extern "C" void kernel_launch(void* const* d_in, const int* in_sizes, int n_in,
                              void* d_out, int out_size, void* d_ws, size_t ws_size,
                              hipStream_t stream) {
    const float* img = (const float*)d_in[0];
    const float* flo = (const float*)d_in[1];
    float* out = (float*)d_out;

    const int grid = BN * (HN / R) * CSPLIT;   // 8*32*4 = 1024 blocks
    warp_kernel<<<grid, TPB, 0, stream>>>(img, flo, out);
}